// Round 2
// baseline (572.865 us; speedup 1.0000x reference)
//
#include <hip/hip_runtime.h>

// ---------------------------------------------------------------------------
// CrossAttention on MI355X (gfx950) — round 3 (resubmit; prior run was an
// infra failure, not a kernel verdict): single fused kernel.
//
//  * KV stays in LDS (no 268 MB ws round-trip, no kernel serialization).
//  * Staging: float4 coalesced loads + in-register 4x4 transpose (was 32
//    scalar strided loads/thread -> latency-bound, MfmaUtil 7%).
//  * out_o broadcast: LDS f32 transpose -> f32x4 regs; agent iteration l
//    stores the l-th broadcast copy (stores stream under the agent loop).
//  * T14: next agent's x_o tile prefetched into regs right after each
//    barrier so the GEMM phase covers the HBM latency.
//
// ws: [WCQ 512x256 bf16][WKV 512x256][WOET 256x256]  (weights only, 640 KB)
// ---------------------------------------------------------------------------

typedef unsigned short u16;
typedef u16  u16x8 __attribute__((ext_vector_type(8)));
typedef u16  u16x4 __attribute__((ext_vector_type(4)));
typedef __bf16 bf16x8 __attribute__((ext_vector_type(8)));
typedef float f32x4 __attribute__((ext_vector_type(4)));

#define XS  264   // LDS stride (u16) for 256-wide bf16 tiles
#define KVS 520   // LDS stride (u16) for 512-wide KV tile
#define YS  36    // LDS stride (f32) for 256x32 f32 transpose buffer (16B-aligned rows)

__device__ __forceinline__ u16 f2bf(float f) {
  union { float f; unsigned u; } t; t.f = f;
  unsigned r = t.u + 0x7FFF + ((t.u >> 16) & 1);
  return (u16)(r >> 16);
}
__device__ __forceinline__ float bf2f(u16 x) {
  union { unsigned u; float f; } t; t.u = ((unsigned)x) << 16;
  return t.f;
}

// D[o][n] = sum_c WT[o][c]*X[n][c]; rows = MT*4*16, N = 32, K = 256.
// WT read from global (L2-resident weights), X from LDS [n][XS].
template <int MT>
__device__ __forceinline__ void gemm_run(const u16* __restrict__ WT,
                                         const u16* __restrict__ X,
                                         int wave, int col, int quad,
                                         f32x4 (&acc)[MT][2]) {
#pragma unroll
  for (int mt = 0; mt < MT; ++mt)
#pragma unroll
    for (int nt = 0; nt < 2; ++nt)
      acc[mt][nt] = (f32x4)(0.0f);
  for (int ks = 0; ks < 8; ++ks) {
    bf16x8 bfr[2];
#pragma unroll
    for (int nt = 0; nt < 2; ++nt)
      bfr[nt] = __builtin_bit_cast(
          bf16x8, *(const u16x8*)&X[(nt * 16 + col) * XS + ks * 32 + quad * 8]);
#pragma unroll
    for (int mt = 0; mt < MT; ++mt) {
      const int m = (wave * MT + mt) * 16 + col;
      bf16x8 afr = __builtin_bit_cast(
          bf16x8, *(const u16x8*)&WT[m * 256 + ks * 32 + quad * 8]);
#pragma unroll
      for (int nt = 0; nt < 2; ++nt)
        acc[mt][nt] = __builtin_amdgcn_mfma_f32_16x16x32_bf16(
            afr, bfr[nt], acc[mt][nt], 0, 0, 0);
    }
  }
}

// ---------------------------------------------------------------------------
// Setup: WCQ rows 0..255 = fused (Wv_ego @ W_out_other)^T, rows 256..511 = Wq^T
// ---------------------------------------------------------------------------
__global__ void ca_setup_fuse(const float* __restrict__ Wqkv_e,
                              const float* __restrict__ Woo,
                              u16* __restrict__ WCQ) {
  const int c = blockIdx.x, o = threadIdx.x;
  __shared__ float wv[256];
  wv[o] = Wqkv_e[c * 768 + 512 + o];
  __syncthreads();
  float s = 0.f;
#pragma unroll 8
  for (int j = 0; j < 256; ++j) s += wv[j] * Woo[j * 256 + o];
  WCQ[o * 256 + c] = f2bf(s);
}

__global__ void ca_setup_trans(const float* __restrict__ Wqkv_e,
                               const float* __restrict__ Wqkv_o,
                               const float* __restrict__ Woe,
                               u16* __restrict__ WCQ, u16* __restrict__ WKV,
                               u16* __restrict__ WOET) {
  const int id = blockIdx.x;    // 0..1023
  const int c = threadIdx.x;    // 0..255
  const int o = id & 255;
  const int sec = id >> 8;
  if (sec == 0)        WCQ[(256 + o) * 256 + c]  = f2bf(Wqkv_e[c * 768 + o]);
  else if (sec == 1)   WKV[o * 256 + c]          = f2bf(Wqkv_o[c * 768 + 256 + o]);
  else if (sec == 2)   WKV[(256 + o) * 256 + c]  = f2bf(Wqkv_o[c * 768 + 512 + o]);
  else                 WOET[o * 256 + c]         = f2bf(Woe[c * 256 + o]);
}

// ---------------------------------------------------------------------------
// Tile staging: 32 pixels x 256 ch, f32 [c][64] global -> bf16 [n][c] LDS.
// Thread t handles 2 micro-tiles of 4c x 4n: coalesced float4 loads (8 lanes
// cover a 128 B half-row), in-register transpose, ds_write_b64.
// ---------------------------------------------------------------------------
__device__ __forceinline__ void tile_load(const float* __restrict__ src, int t,
                                          f32x4 (&g)[2][4]) {
#pragma unroll
  for (int it = 0; it < 2; ++it) {
    const int id = t + it * 256;
    const int n0 = (id & 7) * 4, c0 = (id >> 3) * 4;
#pragma unroll
    for (int i = 0; i < 4; ++i)
      g[it][i] = *(const f32x4*)&src[(c0 + i) * 64 + n0];
  }
}
__device__ __forceinline__ void tile_write(const f32x4 (&g)[2][4],
                                           u16* __restrict__ xbuf, int t) {
#pragma unroll
  for (int it = 0; it < 2; ++it) {
    const int id = t + it * 256;
    const int n0 = (id & 7) * 4, c0 = (id >> 3) * 4;
#pragma unroll
    for (int n = 0; n < 4; ++n) {
      u16x4 p;
#pragma unroll
      for (int i = 0; i < 4; ++i) p[i] = f2bf(g[it][i][n]);
      *(u16x4*)&xbuf[(n0 + n) * XS + c0] = p;
    }
  }
}

// ---------------------------------------------------------------------------
// One agent step: stage gcur -> xbuf, fire out_o copy L, barrier, prefetch
// agent Lnxt into gnxt (hidden under GEMM), KV GEMM -> kvbuf, barrier,
// online-softmax update from kvbuf.
// ---------------------------------------------------------------------------
__device__ __forceinline__ void agent_step(
    int L, const f32x4 (&gcur)[2][4], f32x4 (&gnxt)[2][4], int Lnxt,
    const float* __restrict__ xo_base, u16* __restrict__ xbuf,
    u16* __restrict__ kvbuf, const u16* __restrict__ WKV,
    float* __restrict__ outO, size_t obase, const f32x4 (&yreg)[8],
    const u16x8 (&qp)[4], float (&oacc)[32], float& m_run, float& s_run,
    int t, int wave, int col, int quad, int an, int ah) {
  tile_write(gcur, xbuf, t);
  // out_o broadcast copy for agent L (fire-and-forget, drains at barrier)
#pragma unroll
  for (int it = 0; it < 8; ++it)
    *(f32x4*)&outO[obase + (size_t)L * 524288 + it * 2048] = yreg[it];
  __syncthreads();

  // prefetch next agent tile (latency hidden under the GEMM below)
  tile_load(xo_base + (size_t)Lnxt * 524288, t, gnxt);

  f32x4 acc[8][2];
  gemm_run<8>(WKV, xbuf, wave, col, quad, acc);
#pragma unroll
  for (int mt = 0; mt < 8; ++mt) {
    const int o = (wave * 8 + mt) * 16 + quad * 4;
#pragma unroll
    for (int nt = 0; nt < 2; ++nt) {
      const int n = nt * 16 + col;
      u16x4 pk;
#pragma unroll
      for (int r = 0; r < 4; ++r) pk[r] = f2bf(acc[mt][nt][r]);
      *(u16x4*)&kvbuf[n * KVS + o] = pk;
    }
  }
  __syncthreads();

  // online softmax update (thread = pixel an, head ah)
  u16x8 ck[4], cv[4];
#pragma unroll
  for (int jj = 0; jj < 4; ++jj) {
    ck[jj] = *(const u16x8*)&kvbuf[an * KVS + ah * 32 + jj * 8];
    cv[jj] = *(const u16x8*)&kvbuf[an * KVS + 256 + ah * 32 + jj * 8];
  }
  float sc = 0.f;
#pragma unroll
  for (int jj = 0; jj < 4; ++jj)
#pragma unroll
    for (int e = 0; e < 8; ++e) sc += bf2f(qp[jj][e]) * bf2f(ck[jj][e]);
  sc *= 0.17677669529663687f;
  const float mnew = fmaxf(m_run, sc);
  const float p = __expf(sc - mnew);
  const float al = __expf(m_run - mnew);
  s_run = s_run * al + p;
#pragma unroll
  for (int jj = 0; jj < 4; ++jj)
#pragma unroll
    for (int e = 0; e < 8; ++e)
      oacc[jj * 8 + e] = oacc[jj * 8 + e] * al + p * bf2f(cv[jj][e]);
  m_run = mnew;
}

// ---------------------------------------------------------------------------
// Fused kernel: grid = 512 (bk, nh), 256 threads, 2 blocks/CU.
// ---------------------------------------------------------------------------
__global__ __launch_bounds__(256, 2) void ca_fused(
    const float* __restrict__ ego, const float* __restrict__ other,
    const float* __restrict__ b_oo, const float* __restrict__ b_oe,
    const u16* __restrict__ WCQ, const u16* __restrict__ WKV,
    const u16* __restrict__ WOET, float* __restrict__ out) {
  const int gid = blockIdx.x;
  const int bk = gid >> 1, nh = gid & 1;
  const int b = bk >> 5, kk = bk & 31;
  const int t = threadIdx.x;
  const int lane = t & 63, wave = t >> 6;
  const int col = lane & 15, quad = lane >> 4;
  const int an = t & 31, ah = t >> 5;

  __shared__ u16 xbuf[32 * XS];                       // 16896 B
  __shared__ __align__(16) char ubuf[256 * YS * 4];   // 36864 B  (>= 32*KVS*2)
  __shared__ u16 qbuf[32 * XS];                       // 16896 B
  u16*   kvbuf = (u16*)ubuf;
  float* ybuf  = (float*)ubuf;

  const float* xe_src  = ego   + ((size_t)(bk) * 256) * 64 + nh * 32;
  const float* xo_base = other + ((size_t)((b * 8) * 32 + kk) * 256) * 64 + nh * 32;
  float* outO = out + 4194304;

  // ---- phase 0: stage x_e ------------------------------------------------
  f32x4 gA[2][4], gB[2][4];
  tile_load(xe_src, t, gA);
  tile_write(gA, xbuf, t);
  __syncthreads();

  // prefetch agent 0 (hidden under the xe-GEMM)
  tile_load(xo_base, t, gB);

  // ---- phase 1: xe-GEMM (fused 256 rows + q 256 rows) --------------------
  {
    f32x4 acc[8][2];
    gemm_run<8>(WCQ, xbuf, wave, col, quad, acc);
    if (wave < 2) {           // fused rows -> ybuf f32 [o][YS] (transpose buf)
#pragma unroll
      for (int mt = 0; mt < 8; ++mt) {
        const int o = (wave * 8 + mt) * 16 + quad * 4;
#pragma unroll
        for (int nt = 0; nt < 2; ++nt) {
          const int n = nt * 16 + col;
#pragma unroll
          for (int r = 0; r < 4; ++r) ybuf[(o + r) * YS + n] = acc[mt][nt][r];
        }
      }
    } else {                  // q rows -> qbuf bf16 [n][o]
#pragma unroll
      for (int mt = 0; mt < 8; ++mt) {
        const int o = ((wave - 2) * 8 + mt) * 16 + quad * 4;
#pragma unroll
        for (int nt = 0; nt < 2; ++nt) {
          const int n = nt * 16 + col;
          u16x4 pq;
#pragma unroll
          for (int r = 0; r < 4; ++r) pq[r] = f2bf(acc[mt][nt][r]);
          *(u16x4*)&qbuf[n * XS + o] = pq;
        }
      }
    }
  }
  __syncthreads();

  // ---- phase 2: q -> regs; Y transposed slice -> regs (+bias) ------------
  u16x8 qp[4];
#pragma unroll
  for (int jj = 0; jj < 4; ++jj)
    qp[jj] = *(const u16x8*)&qbuf[an * XS + ah * 32 + jj * 8];

  const int n4 = (t & 7) * 4, cb = t >> 3;
  f32x4 yreg[8];
#pragma unroll
  for (int it = 0; it < 8; ++it) {
    const int C = cb + it * 32;
    f32x4 v = *(const f32x4*)&ybuf[C * YS + n4];
    const float bias = b_oo[C];
#pragma unroll
    for (int e = 0; e < 4; ++e) v[e] += bias;
    yreg[it] = v;
  }
  __syncthreads();   // ybuf now dead -> region reused as kvbuf

  // per-thread out_o store base: [(b*8+l)*32+kk][C][64] with C = cb+it*32
  const size_t obase = (size_t)((b * 8) * 32 + kk) * 16384 + cb * 64 + nh * 32 + n4;

  // ---- phase 3: agent loop (2-agent unroll; static gA/gB double buffer) --
  float m_run = -3.0e38f, s_run = 0.f;
  float oacc[32];
#pragma unroll
  for (int c = 0; c < 32; ++c) oacc[c] = 0.f;

#pragma unroll 1
  for (int l = 0; l < 8; l += 2) {
    agent_step(l,     gB, gA, l + 1,                  xo_base, xbuf, kvbuf, WKV,
               outO, obase, yreg, qp, oacc, m_run, s_run,
               t, wave, col, quad, an, ah);
    agent_step(l + 1, gA, gB, (l + 2 < 8 ? l + 2 : 7), xo_base, xbuf, kvbuf, WKV,
               outO, obase, yreg, qp, oacc, m_run, s_run,
               t, wave, col, quad, an, ah);
  }

  // ---- phase 4: normalize, out_e GEMM, vectorized stores -----------------
  {
    const float inv = 1.f / s_run;
#pragma unroll
    for (int jj = 0; jj < 4; ++jj) {
      u16x8 pa;
#pragma unroll
      for (int e = 0; e < 8; ++e) pa[e] = f2bf(oacc[jj * 8 + e] * inv);
      *(u16x8*)&xbuf[an * XS + ah * 32 + jj * 8] = pa;
    }
  }
  __syncthreads();

  {
    f32x4 acc[4][2];
    gemm_run<4>(WOET, xbuf, wave, col, quad, acc);
#pragma unroll
    for (int mt = 0; mt < 4; ++mt) {
      const int o = (wave * 4 + mt) * 16 + quad * 4;
#pragma unroll
      for (int nt = 0; nt < 2; ++nt) {
        const int n = nt * 16 + col;
#pragma unroll
        for (int r = 0; r < 4; ++r) ybuf[(o + r) * YS + n] = acc[mt][nt][r];
      }
    }
  }
  __syncthreads();

#pragma unroll
  for (int it = 0; it < 8; ++it) {
    const int C = cb + it * 32;
    f32x4 v = *(const f32x4*)&ybuf[C * YS + n4];
    const float bias = b_oe[C];
#pragma unroll
    for (int e = 0; e < 4; ++e) v[e] += bias;
    *(f32x4*)&out[((size_t)(bk * 256 + C)) * 64 + nh * 32 + n4] = v;
  }
}

// ---------------------------------------------------------------------------
extern "C" void kernel_launch(void* const* d_in, const int* in_sizes, int n_in,
                              void* d_out, int out_size, void* d_ws,
                              size_t ws_size, hipStream_t stream) {
  const float* ego    = (const float*)d_in[0];
  const float* other  = (const float*)d_in[1];
  const float* Wqkv_e = (const float*)d_in[2];
  const float* Wqkv_o = (const float*)d_in[3];
  const float* Woe    = (const float*)d_in[4];
  const float* boe    = (const float*)d_in[5];
  const float* Woo    = (const float*)d_in[6];
  const float* boo    = (const float*)d_in[7];
  float* out = (float*)d_out;

  u16* WCQ  = (u16*)d_ws;            // [512][256]
  u16* WKV  = WCQ + 512 * 256;       // [512][256]
  u16* WOET = WKV + 512 * 256;       // [256][256]

  ca_setup_fuse<<<256, 256, 0, stream>>>(Wqkv_e, Woo, WCQ);
  ca_setup_trans<<<1024, 256, 0, stream>>>(Wqkv_e, Wqkv_o, Woe, WCQ, WKV, WOET);
  ca_fused<<<512, 256, 0, stream>>>(ego, other, boo, boe, WCQ, WKV, WOET, out);
}